// Round 5
// baseline (812.474 us; speedup 1.0000x reference)
//
#include <hip/hip_runtime.h>
#include <hip/hip_bf16.h>
#include <math.h>

using bf16 = __hip_bfloat16;
typedef __attribute__((ext_vector_type(8))) short short8;
typedef __attribute__((ext_vector_type(4))) float f32x4;

constexpr int nB = 1024, nS = 30, nE = 300, nD = 512, nH = 8, nL = 4, nDK = 64;
constexpr int nTOK = nB * nS;  // 30720
constexpr float kSqrtD = 22.627416997969522f;    // sqrt(512)
constexpr float kPEc   = -0.03597789207803244f;  // -2*ln(10000)/512

__device__ inline unsigned short bfbits(float f) {
  bf16 h = __float2bfloat16(f);
  return *(unsigned short*)&h;
}
__device__ inline float b2f(short s) {
  return __uint_as_float(((unsigned)(unsigned short)s) << 16);
}
__device__ inline void gload16(const void* g, void* lds) {
  __builtin_amdgcn_global_load_lds(
      (const __attribute__((address_space(1))) unsigned int*)g,
      (__attribute__((address_space(3))) unsigned int*)lds, 16, 0, 0);
}

// ---------------- small converters ----------------
__global__ __launch_bounds__(256) void cvt_kernel(const float* __restrict__ s,
                                                  bf16* __restrict__ d, int n4) {
  int i = blockIdx.x * 256 + threadIdx.x;
  if (i < n4) {
    float4 v = ((const float4*)s)[i];
    ushort4 u;
    u.x = bfbits(v.x); u.y = bfbits(v.y); u.z = bfbits(v.z); u.w = bfbits(v.w);
    ((ushort4*)d)[i] = u;
  }
}

__global__ __launch_bounds__(256) void cvt_pad_win(const float* __restrict__ s,
                                                   bf16* __restrict__ d) {
  int row = blockIdx.x;  // 512
  for (int e = threadIdx.x; e < 320; e += 256)
    d[row * 320 + e] = __float2bfloat16((e < nE) ? s[row * nE + e] : 0.f);
}

__global__ __launch_bounds__(256) void pe_kernel(float* __restrict__ pe) {
  int s = blockIdx.x;  // 30
  for (int dd = threadIdx.x; dd < nD; dd += 256) {
    float ang = (float)s * expf((float)(dd >> 1) * kPEc);
    pe[s * nD + dd] = (dd & 1) ? cosf(ang) : sinf(ang);
  }
}

// gather emb rows -> bf16 [nTOK][320] (K padded 300->320 with zeros)
__global__ __launch_bounds__(256) void gather_kernel(const int* __restrict__ x,
                                                     const float* __restrict__ emb,
                                                     bf16* __restrict__ a) {
  int g = blockIdx.x * 256 + threadIdx.x;  // 30720*40 slots
  int t = g / 40, ch = g - 40 * t;
  float4 v0 = make_float4(0.f, 0.f, 0.f, 0.f), v1 = v0;
  const float* src = emb + (size_t)x[t] * nE + ch * 8;
  if (ch < 37) { v0 = *(const float4*)src; v1 = *(const float4*)(src + 4); }
  else if (ch == 37) { v0 = *(const float4*)src; }
  ushort4 u0, u1;
  u0.x = bfbits(v0.x); u0.y = bfbits(v0.y); u0.z = bfbits(v0.z); u0.w = bfbits(v0.w);
  u1.x = bfbits(v1.x); u1.y = bfbits(v1.y); u1.z = bfbits(v1.z); u1.w = bfbits(v1.w);
  bf16* dst = a + (size_t)t * 320 + ch * 8;
  *(ushort4*)dst = u0;
  *(ushort4*)(dst + 4) = u1;
}

// ---------------- MFMA GEMM tile 64x128: C = A[M,KA] @ W[512,KA]^T ----------------
// EPI 0: y = (acc + bias)*sqrtD + pe[row%30][col]     (embed, no resid)
// EPI 1: y = acc + bias? + resid                      (pre-LN tmp)
// out is bf16. Double-buffered LDS, counted vmcnt.
template <int KA, int EPI>
__global__ __launch_bounds__(256, 4) void gemm_tile(
    const bf16* __restrict__ A, const bf16* __restrict__ W,
    const float* __restrict__ bias, const bf16* __restrict__ resid,
    const float* __restrict__ pe, bf16* __restrict__ out) {
  __shared__ __align__(16) char smem[24576];  // 2 x (As 4KB + Ws 8KB)
  const int tid = threadIdx.x, lane = tid & 63, w = tid >> 6;
  const int q = lane >> 4, c = lane & 15;
  const int m0 = blockIdx.x * 64, n0 = blockIdx.y * 128;
  constexpr int NK = KA / 32;

  f32x4 acc[4][2];
#pragma unroll
  for (int i = 0; i < 4; ++i)
#pragma unroll
    for (int j = 0; j < 2; ++j) acc[i][j] = (f32x4){0.f, 0.f, 0.f, 0.f};

  // stage K-step ks into buffer buf: 3 gload16 per wave
  auto stage = [&](int ks, int buf) {
    char* base = smem + buf * 12288;
    gload16(A + (size_t)(m0 + lane) * KA + ks * 32 + w * 8, base + w * 1024);
#pragma unroll
    for (int j = 0; j < 2; ++j) {
      const int idx = w * 2 + j;
      const int kc = idx >> 1, hal = idx & 1;
      gload16(W + (size_t)(n0 + hal * 64 + lane) * KA + ks * 32 + kc * 8,
              base + 4096 + idx * 1024);
    }
  };

  stage(0, 0);
  for (int ks = 0; ks < NK; ++ks) {
    const int cur = ks & 1;
    if (ks + 1 < NK) {
      stage(ks + 1, cur ^ 1);
      asm volatile("s_waitcnt vmcnt(3)" ::: "memory");
    } else {
      asm volatile("s_waitcnt vmcnt(0)" ::: "memory");
    }
    __builtin_amdgcn_s_barrier();
    asm volatile("" ::: "memory");
    const bf16* As = (const bf16*)(smem + cur * 12288);
    const bf16* Ws = (const bf16*)(smem + cur * 12288 + 4096);
    short8 af[4], bfr[2];
#pragma unroll
    for (int mt = 0; mt < 4; ++mt)
      af[mt] = *(const short8*)(As + (q * 64 + mt * 16 + c) * 8);
#pragma unroll
    for (int nt = 0; nt < 2; ++nt)
      bfr[nt] = *(const short8*)(Ws + (q * 128 + w * 32 + nt * 16 + c) * 8);
#pragma unroll
    for (int mt = 0; mt < 4; ++mt)
#pragma unroll
      for (int nt = 0; nt < 2; ++nt)
        acc[mt][nt] = __builtin_amdgcn_mfma_f32_16x16x32_bf16(af[mt], bfr[nt], acc[mt][nt], 0, 0, 0);
    asm volatile("" ::: "memory");
    __builtin_amdgcn_s_barrier();
    asm volatile("" ::: "memory");
  }
  __syncthreads();

  // epilogue part 1: bias (+sqrtD for embed), bf16 -> LDS transpose [64][136]
  bf16* tb = (bf16*)smem;
  float bias2[2];
#pragma unroll
  for (int nt = 0; nt < 2; ++nt)
    bias2[nt] = bias ? bias[n0 + w * 32 + nt * 16 + c] : 0.f;
#pragma unroll
  for (int mt = 0; mt < 4; ++mt)
#pragma unroll
    for (int nt = 0; nt < 2; ++nt)
#pragma unroll
      for (int r = 0; r < 4; ++r) {
        float t = acc[mt][nt][r] + bias2[nt];
        if (EPI == 0) t *= kSqrtD;
        tb[(mt * 16 + q * 4 + r) * 136 + w * 32 + nt * 16 + c] = __float2bfloat16(t);
      }
  __syncthreads();

  // epilogue part 2: coalesced row-major readback, +pe or +resid, bf16 store
  const int row = tid >> 2, c4 = tid & 3;
  const int gr = m0 + row;
#pragma unroll
  for (int i = 0; i < 4; ++i) {
    const int cols = c4 * 32 + i * 8;
    short8 v = *(const short8*)&tb[row * 136 + cols];
    float e[8];
#pragma unroll
    for (int j = 0; j < 8; ++j) e[j] = b2f(v[j]);
    if (EPI == 0) {
      const float* pp = pe + (size_t)(gr % nS) * nD + n0 + cols;
      float4 p0 = *(const float4*)pp, p1 = *(const float4*)(pp + 4);
      e[0] += p0.x; e[1] += p0.y; e[2] += p0.z; e[3] += p0.w;
      e[4] += p1.x; e[5] += p1.y; e[6] += p1.z; e[7] += p1.w;
    } else {
      short8 rv = *(const short8*)(resid + (size_t)gr * nD + n0 + cols);
#pragma unroll
      for (int j = 0; j < 8; ++j) e[j] += b2f(rv[j]);
    }
    short8 o;
#pragma unroll
    for (int j = 0; j < 8; ++j) o[j] = (short)bfbits(e[j]);
    *(short8*)(out + (size_t)gr * nD + n0 + cols) = o;
  }
}

// ---------------- row LayerNorm over D=512, bf16 in, bf16 (or final fp32) out ----------------
template <int FINAL>
__global__ __launch_bounds__(256) void ln_bf(
    const bf16* __restrict__ X, const float* __restrict__ g,
    const float* __restrict__ bta, bf16* __restrict__ yb,
    float* __restrict__ yf) {
  const int w = threadIdx.x >> 6, lane = threadIdx.x & 63;
  const int row = blockIdx.x * 4 + w;
  short8 v = *(const short8*)(X + (size_t)row * nD + lane * 8);
  float e[8];
  float s = 0.f, sq = 0.f;
#pragma unroll
  for (int j = 0; j < 8; ++j) {
    e[j] = b2f(v[j]);
    s += e[j]; sq += e[j] * e[j];
  }
#pragma unroll
  for (int off = 1; off < 64; off <<= 1) {
    s += __shfl_xor(s, off);
    sq += __shfl_xor(sq, off);
  }
  const float mu = s * (1.f / nD);
  const float var = sq * (1.f / nD) - mu * mu;
  const float inv = rsqrtf(var + 1e-5f);
  const float4 g0 = *(const float4*)(g + lane * 8);
  const float4 g1 = *(const float4*)(g + lane * 8 + 4);
  const float4 b0 = *(const float4*)(bta + lane * 8);
  const float4 b1 = *(const float4*)(bta + lane * 8 + 4);
  float y[8];
  y[0] = (e[0] - mu) * inv * g0.x + b0.x;
  y[1] = (e[1] - mu) * inv * g0.y + b0.y;
  y[2] = (e[2] - mu) * inv * g0.z + b0.z;
  y[3] = (e[3] - mu) * inv * g0.w + b0.w;
  y[4] = (e[4] - mu) * inv * g1.x + b1.x;
  y[5] = (e[5] - mu) * inv * g1.y + b1.y;
  y[6] = (e[6] - mu) * inv * g1.z + b1.z;
  y[7] = (e[7] - mu) * inv * g1.w + b1.w;
  if (FINAL) {
    float* p = yf + (size_t)row * nD + lane * 8;
    *(float4*)p = make_float4(y[0], y[1], y[2], y[3]);
    *(float4*)(p + 4) = make_float4(y[4], y[5], y[6], y[7]);
  } else {
    short8 o;
#pragma unroll
    for (int j = 0; j < 8; ++j) o[j] = (short)bfbits(y[j]);
    *(short8*)(yb + (size_t)row * nD + lane * 8) = o;
  }
}

// ---------------- fully fused attention per (batch, head), MFMA ----------------
__global__ __launch_bounds__(256) void attn_kernel(
    const bf16* __restrict__ wqb, const bf16* __restrict__ wkb,
    const bf16* __restrict__ wvb, const int* __restrict__ mask,
    const bf16* __restrict__ hin, bf16* __restrict__ aout) {
  const int tid = threadIdx.x, lane = tid & 63, w = tid >> 6;
  const int q = lane >> 4, c = lane & 15;
  const int b = blockIdx.x >> 3, hd = blockIdx.x & 7;

  __shared__ __align__(16) bf16 xs[8][32][8];   // x slice, chunked by k/8
  __shared__ __align__(16) bf16 wq[8][64][8];
  __shared__ __align__(16) bf16 wk[8][64][8];
  __shared__ __align__(16) bf16 wv[8][64][8];
  __shared__ __align__(16) bf16 qb[8][32][8];   // q chunked by dk/8
  __shared__ __align__(16) bf16 kb[8][32][8];
  __shared__ __align__(16) bf16 vt[4][64][8];   // V^T: [j/8][d][j%8]
  __shared__ __align__(16) bf16 pb[4][32][8];   // probs: [j/8][i][j%8]
  __shared__ float ps[32][33];
  __shared__ int msk[32];

  {  // stage x (pad rows 30,31 with zeros)
    int row = tid & 31, k8 = tid >> 5;
    uint4 z = make_uint4(0, 0, 0, 0);
    if (row < nS)
      z = *(const uint4*)(hin + (size_t)(b * nS + row) * nD + hd * nDK + k8 * 8);
    *(uint4*)&xs[k8][row][0] = z;
  }
#pragma unroll
  for (int i = 0; i < 2; ++i) {  // stage weights
    int s = tid + i * 256;
    int row = s & 63, k8 = s >> 6;
    *(uint4*)&wq[k8][row][0] = *(const uint4*)(wqb + row * 64 + k8 * 8);
    *(uint4*)&wk[k8][row][0] = *(const uint4*)(wkb + row * 64 + k8 * 8);
    *(uint4*)&wv[k8][row][0] = *(const uint4*)(wvb + row * 64 + k8 * 8);
  }
  if (tid < nS) msk[tid] = mask[b * nS + tid];
  __syncthreads();

  // q/k/v projections: wave w -> output cols [w*16, w*16+16)
  f32x4 aq[2], ak[2], av[2];
#pragma unroll
  for (int mt = 0; mt < 2; ++mt) {
    aq[mt] = (f32x4){0.f, 0.f, 0.f, 0.f};
    ak[mt] = aq[mt]; av[mt] = aq[mt];
  }
#pragma unroll
  for (int kc = 0; kc < 2; ++kc) {
    short8 xa0 = *(const short8*)&xs[kc * 4 + q][c][0];
    short8 xa1 = *(const short8*)&xs[kc * 4 + q][16 + c][0];
    short8 wqf = *(const short8*)&wq[kc * 4 + q][w * 16 + c][0];
    short8 wkf = *(const short8*)&wk[kc * 4 + q][w * 16 + c][0];
    short8 wvf = *(const short8*)&wv[kc * 4 + q][w * 16 + c][0];
    aq[0] = __builtin_amdgcn_mfma_f32_16x16x32_bf16(xa0, wqf, aq[0], 0, 0, 0);
    aq[1] = __builtin_amdgcn_mfma_f32_16x16x32_bf16(xa1, wqf, aq[1], 0, 0, 0);
    ak[0] = __builtin_amdgcn_mfma_f32_16x16x32_bf16(xa0, wkf, ak[0], 0, 0, 0);
    ak[1] = __builtin_amdgcn_mfma_f32_16x16x32_bf16(xa1, wkf, ak[1], 0, 0, 0);
    av[0] = __builtin_amdgcn_mfma_f32_16x16x32_bf16(xa0, wvf, av[0], 0, 0, 0);
    av[1] = __builtin_amdgcn_mfma_f32_16x16x32_bf16(xa1, wvf, av[1], 0, 0, 0);
  }
  const int dk = w * 16 + c;
#pragma unroll
  for (int mt = 0; mt < 2; ++mt)
#pragma unroll
    for (int r = 0; r < 4; ++r) {
      int i = mt * 16 + q * 4 + r;
      qb[dk >> 3][i][dk & 7] = __float2bfloat16(aq[mt][r]);
      kb[dk >> 3][i][dk & 7] = __float2bfloat16(ak[mt][r]);
      vt[i >> 3][dk][i & 7] = __float2bfloat16(av[mt][r]);
    }
  __syncthreads();

  // scores: wave w -> row-block w>>1, col-block w&1
  {
    f32x4 sc = (f32x4){0.f, 0.f, 0.f, 0.f};
    const int is0 = (w >> 1) * 16, js0 = (w & 1) * 16;
#pragma unroll
    for (int kc = 0; kc < 2; ++kc) {
      short8 a = *(const short8*)&qb[kc * 4 + q][is0 + c][0];
      short8 bb = *(const short8*)&kb[kc * 4 + q][js0 + c][0];
      sc = __builtin_amdgcn_mfma_f32_16x16x32_bf16(a, bb, sc, 0, 0, 0);
    }
    int j = js0 + c;
    bool live = (j < nS) && (msk[j] != 0);
#pragma unroll
    for (int r = 0; r < 4; ++r) {
      int i = is0 + q * 4 + r;
      ps[i][j] = live ? sc[r] * 0.125f : -1e9f;
    }
  }
  __syncthreads();

  // softmax (rows < 30), 8 lanes per row
  if (tid < nS * 8) {
    int r = tid >> 3, cc = tid & 7;
    float m = -1e30f;
    for (int j = cc; j < nS; j += 8) m = fmaxf(m, ps[r][j]);
#pragma unroll
    for (int o = 1; o < 8; o <<= 1) m = fmaxf(m, __shfl_xor(m, o));
    float sum = 0.f;
    for (int j = cc; j < nS; j += 8) sum += __expf(ps[r][j] - m);
#pragma unroll
    for (int o = 1; o < 8; o <<= 1) sum += __shfl_xor(sum, o);
    float inv = 1.f / sum;
    for (int j = cc; j < nS; j += 8)
      pb[j >> 3][r][j & 7] = __float2bfloat16(__expf(ps[r][j] - m) * inv);
    if (cc >= 6) pb[3][r][cc] = __float2bfloat16(0.f);  // zero k-slots j=30,31
  }
  __syncthreads();

  // PV: wave w -> d-cols [w*16, w*16+16)
  {
    f32x4 o0 = (f32x4){0.f, 0.f, 0.f, 0.f}, o1 = o0;
    short8 pa0 = *(const short8*)&pb[q][c][0];
    short8 pa1 = *(const short8*)&pb[q][16 + c][0];
    short8 vb = *(const short8*)&vt[q][w * 16 + c][0];
    o0 = __builtin_amdgcn_mfma_f32_16x16x32_bf16(pa0, vb, o0, 0, 0, 0);
    o1 = __builtin_amdgcn_mfma_f32_16x16x32_bf16(pa1, vb, o1, 0, 0, 0);
#pragma unroll
    for (int r = 0; r < 4; ++r) {
      int i0 = q * 4 + r;
      aout[(size_t)(b * nS + i0) * nD + hd * nDK + dk] = __float2bfloat16(o0[r]);
      int i1 = 16 + q * 4 + r;
      if (i1 < nS)
        aout[(size_t)(b * nS + i1) * nD + hd * nDK + dk] = __float2bfloat16(o1[r]);
    }
  }
}

extern "C" void kernel_launch(void* const* d_in, const int* in_sizes, int n_in,
                              void* d_out, int out_size, void* d_ws, size_t ws_size,
                              hipStream_t stream) {
  const int*   x    = (const int*)d_in[0];
  const int*   mask = (const int*)d_in[1];
  const float* emb  = (const float*)d_in[2];
  const float* W_in = (const float*)d_in[3];
  const float* b_in = (const float*)d_in[4];
  const float* Wq   = (const float*)d_in[5];
  const float* Wk   = (const float*)d_in[6];
  const float* Wv   = (const float*)d_in[7];
  const float* Wo   = (const float*)d_in[8];
  const float* Wfc  = (const float*)d_in[9];
  const float* bfc  = (const float*)d_in[10];
  const float* g1   = (const float*)d_in[11];
  const float* be1  = (const float*)d_in[12];
  const float* g2   = (const float*)d_in[13];
  const float* be2  = (const float*)d_in[14];

  // bf16 ping-pong activation buffers live inside d_out (unused until final LN)
  bf16* bufA = (bf16*)d_out;
  bf16* bufB = bufA + (size_t)nTOK * nD;

  char* ws = (char*)d_ws;
  bf16* wo_b  = (bf16*)ws;                  // 4 * 512*512
  bf16* wfc_b = (bf16*)(ws + 2097152);      // 4 * 512*512
  bf16* wq_b  = (bf16*)(ws + 4194304);      // 4 * 64*64
  bf16* wk_b  = (bf16*)(ws + 4227072);
  bf16* wv_b  = (bf16*)(ws + 4259840);
  bf16* win_b = (bf16*)(ws + 4292608);      // [512][320]
  float* pe   = (float*)(ws + 4620288);     // [30][512]
  bf16* a_emb = (bf16*)(ws + 4681728);      // [30720][320]  (dead after embed gemm)
  bf16* tmpf  = (bf16*)(ws + 4681728);      // last-layer FC out (reuses a_emb space)

  cvt_kernel<<<1024, 256, 0, stream>>>(Wo, wo_b, 262144);
  cvt_kernel<<<1024, 256, 0, stream>>>(Wfc, wfc_b, 262144);
  cvt_kernel<<<16, 256, 0, stream>>>(Wq, wq_b, 4096);
  cvt_kernel<<<16, 256, 0, stream>>>(Wk, wk_b, 4096);
  cvt_kernel<<<16, 256, 0, stream>>>(Wv, wv_b, 4096);
  cvt_pad_win<<<512, 256, 0, stream>>>(W_in, win_b);
  pe_kernel<<<30, 256, 0, stream>>>(pe);
  gather_kernel<<<4800, 256, 0, stream>>>(x, emb, a_emb);

  const dim3 ggrid(nTOK / 64, nD / 128);  // (480, 4)
  gemm_tile<320, 0><<<ggrid, 256, 0, stream>>>(a_emb, win_b, b_in, nullptr, pe, bufA);

  bf16* cur = bufA;
  bf16* oth = bufB;
  for (int l = 0; l < nL; ++l) {
    attn_kernel<<<nB * nH, 256, 0, stream>>>(wq_b + l * 4096, wk_b + l * 4096,
                                             wv_b + l * 4096, mask, cur, oth);
    // tmp1 = attn_out @ Wo^T + cur   (in-place over resid: per-cell read->write by same block)
    gemm_tile<512, 1><<<ggrid, 256, 0, stream>>>(oth, wo_b + (size_t)l * 262144,
                                                 nullptr, cur, nullptr, cur);
    ln_bf<0><<<nTOK / 4, 256, 0, stream>>>(cur, g1 + l * nD, be1 + l * nD, cur, nullptr);
    // tmp2 = n1 @ Wfc^T + bfc + n1
    bf16* o2 = (l == nL - 1) ? tmpf : oth;
    gemm_tile<512, 1><<<ggrid, 256, 0, stream>>>(cur, wfc_b + (size_t)l * 262144,
                                                 bfc + l * nD, cur, nullptr, o2);
    if (l < nL - 1) {
      ln_bf<0><<<nTOK / 4, 256, 0, stream>>>(oth, g2 + l * nD, be2 + l * nD, oth, nullptr);
      bf16* t = cur; cur = oth; oth = t;
    } else {
      ln_bf<1><<<nTOK / 4, 256, 0, stream>>>(tmpf, g2 + l * nD, be2 + l * nD,
                                             nullptr, (float*)d_out);
    }
  }
  (void)in_sizes; (void)n_in; (void)out_size; (void)ws_size;
}